// Round 2
// 631.020 us; speedup vs baseline: 1.1957x; 1.1957x over previous
//
#include <hip/hip_runtime.h>
#include <hip/hip_bf16.h>

#define B_    8
#define V_    100000
#define FIN_  32
#define K_    4
#define FOUT_ 64
#define E_    800000
#define NODE_F 256   // B_ * FIN_ elements per node row

typedef __attribute__((ext_vector_type(8))) short bf16x8;
typedef __attribute__((ext_vector_type(4))) float floatx4;

static __device__ inline float bf2f(unsigned short u) {
    unsigned int x = ((unsigned int)u) << 16;
    return __builtin_bit_cast(float, x);
}
static __device__ inline unsigned short f2bf(float f) {
    __hip_bfloat16 h = __float2bfloat16(f);   // RNE
    return __builtin_bit_cast(unsigned short, h);
}

// ---------------- transpose: inputs [B][V][FIN] fp32 -> x0 [V][B][FIN] bf16
__global__ __launch_bounds__(256) void k_transpose(const float* __restrict__ in,
                                                   unsigned short* __restrict__ x0) {
    int tid = blockIdx.x * 256 + threadIdx.x;     // over V_*B_*8 groups of 4
    int f4 = tid & 7;
    int m  = tid >> 3;          // m = v*8 + b
    int v  = m >> 3;
    int b  = m & 7;
    float4 val = ((const float4*)(in + ((size_t)b * V_ + v) * FIN_))[f4];
    ushort4 o;
    o.x = f2bf(val.x); o.y = f2bf(val.y); o.z = f2bf(val.z); o.w = f2bf(val.w);
    ((ushort4*)x0)[tid] = o;
}

// ---------------- weight pre-pack into MFMA A-fragment layout ---------------
// wpack[kq][ot][lane][j] = bf16(W[f = quad*8+j][kq][o = ot*16 + l16])
// (identical value layout to the old B-frag; A/B fragment layouts are
//  symmetric for mfma_f32_16x16x32_bf16, so this serves as the A operand
//  of the transposed GEMM D[o][m] = W^T x^T.)
__global__ __launch_bounds__(256) void k_packw(const float* __restrict__ weight,
                                               unsigned short* __restrict__ wpack) {
    int t = blockIdx.x * 256 + threadIdx.x;   // 0..1023 = (kq,ot,lane)
    int lane = t & 63;
    int ot   = (t >> 6) & 3;
    int kq   = t >> 8;
    int quad = lane >> 4, l16 = lane & 15;
    bf16x8 w;
    #pragma unroll
    for (int j = 0; j < 8; ++j)
        w[j] = (short)f2bf(weight[(size_t)(quad * 8 + j) * (K_ * FOUT_) + kq * FOUT_ + ot * 16 + l16]);
    *((bf16x8*)(wpack + (size_t)t * 8)) = w;
}

// ---------------- CSR build ------------------------------------------------
__global__ __launch_bounds__(256) void k_zero_int(int* __restrict__ p, int n) {
    int t = blockIdx.x * 256 + threadIdx.x;
    if (t < n) p[t] = 0;
}

__global__ __launch_bounds__(256) void k_hist(const int* __restrict__ rows,
                                              int* __restrict__ counts) {
    int e = blockIdx.x * 256 + threadIdx.x;
    if (e < E_) atomicAdd(&counts[rows[e]], 1);
}

__global__ __launch_bounds__(1024) void k_scan1(const int* __restrict__ counts,
                                                int* __restrict__ out,
                                                int* __restrict__ bsums, int n) {
    __shared__ int s[1024];
    int t = threadIdx.x;
    int idx = blockIdx.x * 1024 + t;
    int v = (idx < n) ? counts[idx] : 0;
    s[t] = v;
    __syncthreads();
    for (int off = 1; off < 1024; off <<= 1) {
        int add = (t >= off) ? s[t - off] : 0;
        __syncthreads();
        s[t] += add;
        __syncthreads();
    }
    if (idx < n) out[idx] = s[t] - v;   // exclusive
    if (t == 1023) bsums[blockIdx.x] = s[1023];
}

__global__ __launch_bounds__(128) void k_scan2(const int* __restrict__ bsums,
                                               int* __restrict__ boffs, int nb) {
    __shared__ int s[128];
    int t = threadIdx.x;
    int v = (t < nb) ? bsums[t] : 0;
    s[t] = v;
    __syncthreads();
    for (int off = 1; off < 128; off <<= 1) {
        int add = (t >= off) ? s[t - off] : 0;
        __syncthreads();
        s[t] += add;
        __syncthreads();
    }
    boffs[t] = s[t] - v;
}

__global__ __launch_bounds__(1024) void k_scan3(int* __restrict__ row_ptr,
                                                int* __restrict__ cursor,
                                                const int* __restrict__ boffs, int n) {
    int idx = blockIdx.x * 1024 + threadIdx.x;
    if (idx < n) {
        int r = row_ptr[idx] + boffs[blockIdx.x];
        row_ptr[idx] = r;
        cursor[idx]  = r;
    }
}

__global__ __launch_bounds__(256) void k_scatter(const int* __restrict__ rows,
                                                 const int* __restrict__ cols,
                                                 const float* __restrict__ vals,
                                                 int* __restrict__ cursor,
                                                 int2* __restrict__ e_pack) {
    int e = blockIdx.x * 256 + threadIdx.x;
    if (e < E_) {
        int r = rows[e];
        int pos = atomicAdd(&cursor[r], 1);
        e_pack[pos] = make_int2(cols[e], __float_as_int(vals[e]));
    }
}

// ---------------- SpMM + Chebyshev recurrence (bf16 storage, fp32 accum) ---
// xn[v] = scale * (L @ xc)[v] - (has_prev ? xp[v] : 0)
// 2 edges per wave concurrently: half-wave (32 lanes) x 16B gather each.
// Manual 2x unroll => up to 4 independent gathers in flight per wave.
__global__ __launch_bounds__(256) void k_spmm(const unsigned short* __restrict__ xc,
                                              const unsigned short* __restrict__ xp,
                                              const int* __restrict__ row_ptr,
                                              const int2* __restrict__ ep,
                                              unsigned short* __restrict__ xn,
                                              float scale, int has_prev) {
    int wave = threadIdx.x >> 6;
    int lane = threadIdx.x & 63;
    int half = lane >> 5;        // 0/1: which edge of a pair
    int hl   = lane & 31;        // feature chunk: 8 bf16 per half-lane
    int v = blockIdx.x * 4 + wave;
    if (v >= V_) return;
    int beg = row_ptr[v];
    int end = (v == V_ - 1) ? E_ : row_ptr[v + 1];

    float acc[8] = {0.f, 0.f, 0.f, 0.f, 0.f, 0.f, 0.f, 0.f};
    int e = beg + half;
    // pipelined pairs: two edges of this half in flight
    for (; e + 2 < end; e += 4) {
        int2 p0 = ep[e];
        int2 p1 = ep[e + 2];
        bf16x8 g0 = *((const bf16x8*)(xc + (size_t)p0.x * NODE_F + hl * 8));
        bf16x8 g1 = *((const bf16x8*)(xc + (size_t)p1.x * NODE_F + hl * 8));
        float v0 = __int_as_float(p0.y);
        float v1 = __int_as_float(p1.y);
        #pragma unroll
        for (int j = 0; j < 8; ++j) acc[j] += v0 * bf2f((unsigned short)g0[j]);
        #pragma unroll
        for (int j = 0; j < 8; ++j) acc[j] += v1 * bf2f((unsigned short)g1[j]);
    }
    for (; e < end; e += 2) {
        int2 p = ep[e];
        bf16x8 g = *((const bf16x8*)(xc + (size_t)p.x * NODE_F + hl * 8));
        float vv = __int_as_float(p.y);
        #pragma unroll
        for (int j = 0; j < 8; ++j) acc[j] += vv * bf2f((unsigned short)g[j]);
    }

    // combine the two half-wave partial sums
    #pragma unroll
    for (int j = 0; j < 8; ++j) acc[j] += __shfl_xor(acc[j], 32);

    if (half == 0) {
        float r[8];
        if (has_prev) {
            bf16x8 p = *((const bf16x8*)(xp + (size_t)v * NODE_F + hl * 8));
            #pragma unroll
            for (int j = 0; j < 8; ++j) r[j] = scale * acc[j] - bf2f((unsigned short)p[j]);
        } else {
            #pragma unroll
            for (int j = 0; j < 8; ++j) r[j] = acc[j];
        }
        bf16x8 o;
        #pragma unroll
        for (int j = 0; j < 8; ++j) o[j] = (short)f2bf(r[j]);
        *((bf16x8*)(xn + (size_t)v * NODE_F + hl * 8)) = o;
    }
}

// ---------------- contraction via MFMA (transposed mapping) ----------------
// out[b,v,o] = sum_{k,f} x_k[v,b,f] W[f,k,o] + bias[o]
// GEMM: D = W^T (64x128) * x^T (128x16-per-tile).  M = o (4 tiles of 16),
// N = m-rows (16/tile), Kdim = 128.  A-frags (W) prepacked in wpack,
// B-frag = x row-slab (same 16B contiguous load as before).
// D: col = lane&15 = m-row, row = quad*4+r = o  =>  4 consecutive o per lane
// => float4 stores.  Bias folded into accumulator init.
#define TILES_PER_WAVE 5
__global__ __launch_bounds__(256) void k_contract(const unsigned short* __restrict__ x0,
                                                  const unsigned short* __restrict__ x1,
                                                  const unsigned short* __restrict__ x2,
                                                  const unsigned short* __restrict__ x3,
                                                  const unsigned short* __restrict__ wpack,
                                                  const float* __restrict__ bias,
                                                  float* __restrict__ out) {
    int wave = threadIdx.x >> 6;
    int lane = threadIdx.x & 63;
    int quad = lane >> 4;
    int l16  = lane & 15;
    const unsigned short* xs[4] = {x0, x1, x2, x3};

    // A fragments from prepack: 16 coalesced 16B loads (L1-resident)
    bf16x8 wfrag[4][4];
    #pragma unroll
    for (int kq = 0; kq < 4; ++kq)
        #pragma unroll
        for (int ot = 0; ot < 4; ++ot)
            wfrag[kq][ot] = *((const bf16x8*)(wpack + (size_t)((kq * 4 + ot) * 64 + lane) * 8));

    // bias: per lane 4 consecutive o per ot-tile -> float4
    floatx4 bi[4];
    #pragma unroll
    for (int ot = 0; ot < 4; ++ot)
        bi[ot] = *((const floatx4*)(bias + ot * 16 + quad * 4));

    int wid   = blockIdx.x * 4 + wave;
    int tile0 = wid * TILES_PER_WAVE;
    #pragma unroll 1
    for (int t = 0; t < TILES_PER_WAVE; ++t) {
        int m0 = (tile0 + t) * 16;
        floatx4 acc[4] = {bi[0], bi[1], bi[2], bi[3]};   // bias pre-seeded
        #pragma unroll
        for (int kq = 0; kq < 4; ++kq) {
            bf16x8 xf = *((const bf16x8*)(xs[kq] + (size_t)(m0 + l16) * FIN_ + quad * 8));
            #pragma unroll
            for (int ot = 0; ot < 4; ++ot)
                acc[ot] = __builtin_amdgcn_mfma_f32_16x16x32_bf16(wfrag[kq][ot], xf, acc[ot], 0, 0, 0);
        }
        int m = m0 + l16;
        int v = m >> 3;
        int b = m & 7;
        float* op = out + ((size_t)b * V_ + v) * FOUT_ + quad * 4;
        #pragma unroll
        for (int ot = 0; ot < 4; ++ot)
            *((floatx4*)(op + ot * 16)) = acc[ot];
    }
}

// ---------------- launcher -------------------------------------------------
extern "C" void kernel_launch(void* const* d_in, const int* in_sizes, int n_in,
                              void* d_out, int out_size, void* d_ws, size_t ws_size,
                              hipStream_t stream) {
    const float* inputs  = (const float*)d_in[0];
    const int*   laprows = (const int*)d_in[1];
    const int*   lapcols = (const int*)d_in[2];
    const float* lapvals = (const float*)d_in[3];
    const float* weight  = (const float*)d_in[4];
    const float* bias    = (const float*)d_in[5];
    float* out = (float*)d_out;

    const size_t XN = (size_t)V_ * NODE_F;   // 25.6M bf16 per buffer
    unsigned short* x0 = (unsigned short*)d_ws;
    unsigned short* x1 = x0 + XN;
    unsigned short* x2 = x1 + XN;
    unsigned short* x3 = x2 + XN;
    int* counts  = (int*)(x3 + XN);
    int* row_ptr = counts + V_;
    int* cursor  = row_ptr + V_;
    int* bsums   = cursor + V_;
    int* boffs   = bsums + 128;
    int2* e_pack = (int2*)(boffs + 128);          // 8B-aligned (offset divisible by 8)
    unsigned short* wpack = (unsigned short*)(e_pack + E_);   // 16 KB

    const int NB_SCAN = (V_ + 1023) / 1024;   // 98

    hipLaunchKernelGGL(k_zero_int, dim3((V_ + 255) / 256), dim3(256), 0, stream, counts, V_);
    hipLaunchKernelGGL(k_packw, dim3(4), dim3(256), 0, stream, weight, wpack);
    hipLaunchKernelGGL(k_transpose, dim3((V_ * B_ * 8) / 256), dim3(256), 0, stream, inputs, x0);
    hipLaunchKernelGGL(k_hist, dim3((E_ + 255) / 256), dim3(256), 0, stream, laprows, counts);
    hipLaunchKernelGGL(k_scan1, dim3(NB_SCAN), dim3(1024), 0, stream, counts, row_ptr, bsums, V_);
    hipLaunchKernelGGL(k_scan2, dim3(1), dim3(128), 0, stream, bsums, boffs, NB_SCAN);
    hipLaunchKernelGGL(k_scan3, dim3(NB_SCAN), dim3(1024), 0, stream, row_ptr, cursor, boffs, V_);
    hipLaunchKernelGGL(k_scatter, dim3((E_ + 255) / 256), dim3(256), 0, stream,
                       laprows, lapcols, lapvals, cursor, e_pack);

    // x1 = L x0 ; x2 = 2 L x1 - x0 ; x3 = 2 L x2 - x1
    hipLaunchKernelGGL(k_spmm, dim3(V_ / 4), dim3(256), 0, stream,
                       x0, (const unsigned short*)nullptr, row_ptr, e_pack, x1, 1.0f, 0);
    hipLaunchKernelGGL(k_spmm, dim3(V_ / 4), dim3(256), 0, stream,
                       x1, x0, row_ptr, e_pack, x2, 2.0f, 1);
    hipLaunchKernelGGL(k_spmm, dim3(V_ / 4), dim3(256), 0, stream,
                       x2, x1, row_ptr, e_pack, x3, 2.0f, 1);

    // 50000 m-tiles / (4 waves * 5 tiles) = 2500 blocks
    hipLaunchKernelGGL(k_contract, dim3(2500), dim3(256), 0, stream,
                       x0, x1, x2, x3, wpack, bias, out);
}

// Round 3
// 626.503 us; speedup vs baseline: 1.2043x; 1.0072x over previous
//
#include <hip/hip_runtime.h>
#include <hip/hip_bf16.h>

#define B_    8
#define V_    100000
#define FIN_  32
#define K_    4
#define FOUT_ 64
#define E_    800000
#define NODE_F 256   // B_ * FIN_ elements per node row

typedef __attribute__((ext_vector_type(8))) short bf16x8;
typedef __attribute__((ext_vector_type(4))) float floatx4;

static __device__ inline float bf2f(unsigned short u) {
    unsigned int x = ((unsigned int)u) << 16;
    return __builtin_bit_cast(float, x);
}
static __device__ inline unsigned short f2bf(float f) {
    __hip_bfloat16 h = __float2bfloat16(f);   // RNE
    return __builtin_bit_cast(unsigned short, h);
}

// ---------------- fused prologue: transpose + edge histogram + weight pack --
// transpose: inputs [B][V][FIN] fp32 -> x0 [V][B][FIN] bf16   (all threads)
// hist:      counts[rows[e]]++ for e < E_                      (tid < E_)
// packw:     W -> MFMA fragment layout                         (tid < 1024)
__global__ __launch_bounds__(256) void k_transpose(const float* __restrict__ in,
                                                   unsigned short* __restrict__ x0,
                                                   const int* __restrict__ rows,
                                                   int* __restrict__ counts,
                                                   const float* __restrict__ weight,
                                                   unsigned short* __restrict__ wpack) {
    int tid = blockIdx.x * 256 + threadIdx.x;     // over V_*B_*8 groups of 4
    int f4 = tid & 7;
    int m  = tid >> 3;          // m = v*8 + b
    int v  = m >> 3;
    int b  = m & 7;
    float4 val = ((const float4*)(in + ((size_t)b * V_ + v) * FIN_))[f4];
    ushort4 o;
    o.x = f2bf(val.x); o.y = f2bf(val.y); o.z = f2bf(val.z); o.w = f2bf(val.w);
    ((ushort4*)x0)[tid] = o;

    if (tid < E_) atomicAdd(&counts[rows[tid]], 1);

    if (tid < 1024) {   // wpack[kq][ot][lane][j] = bf16(W[f=quad*8+j][kq][o=ot*16+l16])
        int lane = tid & 63;
        int ot   = (tid >> 6) & 3;
        int kq   = tid >> 8;
        int quad = lane >> 4, l16 = lane & 15;
        bf16x8 w;
        #pragma unroll
        for (int j = 0; j < 8; ++j)
            w[j] = (short)f2bf(weight[(size_t)(quad * 8 + j) * (K_ * FOUT_) + kq * FOUT_ + ot * 16 + l16]);
        *((bf16x8*)(wpack + (size_t)tid * 8)) = w;
    }
}

// ---------------- CSR build ------------------------------------------------
__global__ __launch_bounds__(256) void k_zero_int(int* __restrict__ p, int n) {
    int t = blockIdx.x * 256 + threadIdx.x;
    if (t < n) p[t] = 0;
}

// block-local exclusive scan; writes BOTH row_ptr (read-only) and cursor
// (consumed by scatter's atomicAdd).  Global offset = + boffs[idx>>10],
// applied downstream (k_scatter / k_spmm) -- no third scan pass needed.
__global__ __launch_bounds__(1024) void k_scan1(const int* __restrict__ counts,
                                                int* __restrict__ row_ptr,
                                                int* __restrict__ cursor,
                                                int* __restrict__ bsums, int n) {
    __shared__ int s[1024];
    int t = threadIdx.x;
    int idx = blockIdx.x * 1024 + t;
    int v = (idx < n) ? counts[idx] : 0;
    s[t] = v;
    __syncthreads();
    for (int off = 1; off < 1024; off <<= 1) {
        int add = (t >= off) ? s[t - off] : 0;
        __syncthreads();
        s[t] += add;
        __syncthreads();
    }
    if (idx < n) {
        int r = s[t] - v;   // exclusive, block-local
        row_ptr[idx] = r;
        cursor[idx]  = r;
    }
    if (t == 1023) bsums[blockIdx.x] = s[1023];
}

__global__ __launch_bounds__(128) void k_scan2(const int* __restrict__ bsums,
                                               int* __restrict__ boffs, int nb) {
    __shared__ int s[128];
    int t = threadIdx.x;
    int v = (t < nb) ? bsums[t] : 0;
    s[t] = v;
    __syncthreads();
    for (int off = 1; off < 128; off <<= 1) {
        int add = (t >= off) ? s[t - off] : 0;
        __syncthreads();
        s[t] += add;
        __syncthreads();
    }
    boffs[t] = s[t] - v;
}

__global__ __launch_bounds__(256) void k_scatter(const int* __restrict__ rows,
                                                 const int* __restrict__ cols,
                                                 const float* __restrict__ vals,
                                                 int* __restrict__ cursor,
                                                 const int* __restrict__ boffs,
                                                 int2* __restrict__ e_pack) {
    int e = blockIdx.x * 256 + threadIdx.x;
    if (e < E_) {
        int r = rows[e];
        int pos = atomicAdd(&cursor[r], 1) + boffs[r >> 10];
        e_pack[pos] = make_int2(cols[e], __float_as_int(vals[e]));
    }
}

// ---------------- SpMM + Chebyshev recurrence (bf16 storage, fp32 accum) ---
// xn[v] = scale * (L @ xc)[v] - (has_prev ? xp[v] : 0)
// Half-wave (32 lanes x 16B) per edge; 4-deep pipeline => 8 edges (~= mean
// degree) in flight per wave, 4 KB outstanding.  Accumulation order identical
// to the 2-deep version (edges e, e+2, e+4, e+6 per half, in order).
__global__ __launch_bounds__(256) void k_spmm(const unsigned short* __restrict__ xc,
                                              const unsigned short* __restrict__ xp,
                                              const int* __restrict__ row_ptr,
                                              const int* __restrict__ boffs,
                                              const int2* __restrict__ ep,
                                              unsigned short* __restrict__ xn,
                                              float scale, int has_prev) {
    int wave = threadIdx.x >> 6;
    int lane = threadIdx.x & 63;
    int half = lane >> 5;        // 0/1: edge parity within the pipeline
    int hl   = lane & 31;        // feature chunk: 8 bf16 per half-lane
    int v = blockIdx.x * 4 + wave;
    if (v >= V_) return;
    int beg = row_ptr[v] + boffs[v >> 10];
    int end = (v == V_ - 1) ? E_ : row_ptr[v + 1] + boffs[(v + 1) >> 10];

    float acc[8] = {0.f, 0.f, 0.f, 0.f, 0.f, 0.f, 0.f, 0.f};
    int e = beg + half;
    // 4-deep: 4 gathers per half in flight (8 edges per wave iteration)
    for (; e + 6 < end; e += 8) {
        int2 p0 = ep[e];
        int2 p1 = ep[e + 2];
        int2 p2 = ep[e + 4];
        int2 p3 = ep[e + 6];
        bf16x8 g0 = *((const bf16x8*)(xc + (size_t)p0.x * NODE_F + hl * 8));
        bf16x8 g1 = *((const bf16x8*)(xc + (size_t)p1.x * NODE_F + hl * 8));
        bf16x8 g2 = *((const bf16x8*)(xc + (size_t)p2.x * NODE_F + hl * 8));
        bf16x8 g3 = *((const bf16x8*)(xc + (size_t)p3.x * NODE_F + hl * 8));
        float v0 = __int_as_float(p0.y);
        float v1 = __int_as_float(p1.y);
        float v2 = __int_as_float(p2.y);
        float v3 = __int_as_float(p3.y);
        #pragma unroll
        for (int j = 0; j < 8; ++j) acc[j] += v0 * bf2f((unsigned short)g0[j]);
        #pragma unroll
        for (int j = 0; j < 8; ++j) acc[j] += v1 * bf2f((unsigned short)g1[j]);
        #pragma unroll
        for (int j = 0; j < 8; ++j) acc[j] += v2 * bf2f((unsigned short)g2[j]);
        #pragma unroll
        for (int j = 0; j < 8; ++j) acc[j] += v3 * bf2f((unsigned short)g3[j]);
    }
    for (; e + 2 < end; e += 4) {   // 2-deep remainder
        int2 p0 = ep[e];
        int2 p1 = ep[e + 2];
        bf16x8 g0 = *((const bf16x8*)(xc + (size_t)p0.x * NODE_F + hl * 8));
        bf16x8 g1 = *((const bf16x8*)(xc + (size_t)p1.x * NODE_F + hl * 8));
        float v0 = __int_as_float(p0.y);
        float v1 = __int_as_float(p1.y);
        #pragma unroll
        for (int j = 0; j < 8; ++j) acc[j] += v0 * bf2f((unsigned short)g0[j]);
        #pragma unroll
        for (int j = 0; j < 8; ++j) acc[j] += v1 * bf2f((unsigned short)g1[j]);
    }
    for (; e < end; e += 2) {       // scalar remainder
        int2 p = ep[e];
        bf16x8 g = *((const bf16x8*)(xc + (size_t)p.x * NODE_F + hl * 8));
        float vv = __int_as_float(p.y);
        #pragma unroll
        for (int j = 0; j < 8; ++j) acc[j] += vv * bf2f((unsigned short)g[j]);
    }

    // combine the two half-wave partial sums
    #pragma unroll
    for (int j = 0; j < 8; ++j) acc[j] += __shfl_xor(acc[j], 32);

    if (half == 0) {
        float r[8];
        if (has_prev) {
            bf16x8 p = *((const bf16x8*)(xp + (size_t)v * NODE_F + hl * 8));
            #pragma unroll
            for (int j = 0; j < 8; ++j) r[j] = scale * acc[j] - bf2f((unsigned short)p[j]);
        } else {
            #pragma unroll
            for (int j = 0; j < 8; ++j) r[j] = acc[j];
        }
        bf16x8 o;
        #pragma unroll
        for (int j = 0; j < 8; ++j) o[j] = (short)f2bf(r[j]);
        *((bf16x8*)(xn + (size_t)v * NODE_F + hl * 8)) = o;
    }
}

// ---------------- contraction via MFMA (transposed mapping) ----------------
// out[b,v,o] = sum_{k,f} x_k[v,b,f] W[f,k,o] + bias[o]
// GEMM: D = W^T (64x128) * x^T (128x16-per-tile).  A-frags (W) prepacked,
// D: col = lane&15 = m-row, row = quad*4+r = o  =>  float4 stores, bias
// pre-seeded into the accumulator.
#define TILES_PER_WAVE 5
__global__ __launch_bounds__(256) void k_contract(const unsigned short* __restrict__ x0,
                                                  const unsigned short* __restrict__ x1,
                                                  const unsigned short* __restrict__ x2,
                                                  const unsigned short* __restrict__ x3,
                                                  const unsigned short* __restrict__ wpack,
                                                  const float* __restrict__ bias,
                                                  float* __restrict__ out) {
    int wave = threadIdx.x >> 6;
    int lane = threadIdx.x & 63;
    int quad = lane >> 4;
    int l16  = lane & 15;
    const unsigned short* xs[4] = {x0, x1, x2, x3};

    // A fragments from prepack: 16 coalesced 16B loads (L1-resident)
    bf16x8 wfrag[4][4];
    #pragma unroll
    for (int kq = 0; kq < 4; ++kq)
        #pragma unroll
        for (int ot = 0; ot < 4; ++ot)
            wfrag[kq][ot] = *((const bf16x8*)(wpack + (size_t)((kq * 4 + ot) * 64 + lane) * 8));

    // bias: per lane 4 consecutive o per ot-tile -> float4
    floatx4 bi[4];
    #pragma unroll
    for (int ot = 0; ot < 4; ++ot)
        bi[ot] = *((const floatx4*)(bias + ot * 16 + quad * 4));

    int wid   = blockIdx.x * 4 + wave;
    int tile0 = wid * TILES_PER_WAVE;
    #pragma unroll 1
    for (int t = 0; t < TILES_PER_WAVE; ++t) {
        int m0 = (tile0 + t) * 16;
        floatx4 acc[4] = {bi[0], bi[1], bi[2], bi[3]};   // bias pre-seeded
        #pragma unroll
        for (int kq = 0; kq < 4; ++kq) {
            bf16x8 xf = *((const bf16x8*)(xs[kq] + (size_t)(m0 + l16) * FIN_ + quad * 8));
            #pragma unroll
            for (int ot = 0; ot < 4; ++ot)
                acc[ot] = __builtin_amdgcn_mfma_f32_16x16x32_bf16(wfrag[kq][ot], xf, acc[ot], 0, 0, 0);
        }
        int m = m0 + l16;
        int v = m >> 3;
        int b = m & 7;
        float* op = out + ((size_t)b * V_ + v) * FOUT_ + quad * 4;
        #pragma unroll
        for (int ot = 0; ot < 4; ++ot)
            *((floatx4*)(op + ot * 16)) = acc[ot];
    }
}

// ---------------- launcher -------------------------------------------------
extern "C" void kernel_launch(void* const* d_in, const int* in_sizes, int n_in,
                              void* d_out, int out_size, void* d_ws, size_t ws_size,
                              hipStream_t stream) {
    const float* inputs  = (const float*)d_in[0];
    const int*   laprows = (const int*)d_in[1];
    const int*   lapcols = (const int*)d_in[2];
    const float* lapvals = (const float*)d_in[3];
    const float* weight  = (const float*)d_in[4];
    const float* bias    = (const float*)d_in[5];
    float* out = (float*)d_out;

    const size_t XN = (size_t)V_ * NODE_F;   // 25.6M bf16 per buffer
    unsigned short* x0 = (unsigned short*)d_ws;
    unsigned short* x1 = x0 + XN;
    unsigned short* x2 = x1 + XN;
    unsigned short* x3 = x2 + XN;
    int* counts  = (int*)(x3 + XN);
    int* row_ptr = counts + V_;
    int* cursor  = row_ptr + V_;
    int* bsums   = cursor + V_;
    int* boffs   = bsums + 128;
    int2* e_pack = (int2*)(boffs + 128);          // 8B-aligned (offset divisible by 8)
    unsigned short* wpack = (unsigned short*)(e_pack + E_);   // 16 KB

    const int NB_SCAN = (V_ + 1023) / 1024;   // 98

    hipLaunchKernelGGL(k_zero_int, dim3((V_ + 255) / 256), dim3(256), 0, stream, counts, V_);
    hipLaunchKernelGGL(k_transpose, dim3((V_ * B_ * 8) / 256), dim3(256), 0, stream,
                       inputs, x0, laprows, counts, weight, wpack);
    hipLaunchKernelGGL(k_scan1, dim3(NB_SCAN), dim3(1024), 0, stream,
                       counts, row_ptr, cursor, bsums, V_);
    hipLaunchKernelGGL(k_scan2, dim3(1), dim3(128), 0, stream, bsums, boffs, NB_SCAN);
    hipLaunchKernelGGL(k_scatter, dim3((E_ + 255) / 256), dim3(256), 0, stream,
                       laprows, lapcols, lapvals, cursor, boffs, e_pack);

    // x1 = L x0 ; x2 = 2 L x1 - x0 ; x3 = 2 L x2 - x1
    hipLaunchKernelGGL(k_spmm, dim3(V_ / 4), dim3(256), 0, stream,
                       x0, (const unsigned short*)nullptr, row_ptr, boffs, e_pack, x1, 1.0f, 0);
    hipLaunchKernelGGL(k_spmm, dim3(V_ / 4), dim3(256), 0, stream,
                       x1, x0, row_ptr, boffs, e_pack, x2, 2.0f, 1);
    hipLaunchKernelGGL(k_spmm, dim3(V_ / 4), dim3(256), 0, stream,
                       x2, x1, row_ptr, boffs, e_pack, x3, 2.0f, 1);

    // 50000 m-tiles / (4 waves * 5 tiles) = 2500 blocks
    hipLaunchKernelGGL(k_contract, dim3(2500), dim3(256), 0, stream,
                       x0, x1, x2, x3, wpack, bias, out);
}

// Round 4
// 608.845 us; speedup vs baseline: 1.2392x; 1.0290x over previous
//
#include <hip/hip_runtime.h>
#include <hip/hip_bf16.h>

#define B_    8
#define V_    100000
#define FIN_  32
#define K_    4
#define FOUT_ 64
#define E_    800000
#define NODE_F 256   // B_ * FIN_ elements per node row

typedef __attribute__((ext_vector_type(8))) short bf16x8;
typedef __attribute__((ext_vector_type(4))) float floatx4;

static __device__ inline float bf2f(unsigned short u) {
    unsigned int x = ((unsigned int)u) << 16;
    return __builtin_bit_cast(float, x);
}
static __device__ inline unsigned short f2bf(float f) {
    __hip_bfloat16 h = __float2bfloat16(f);   // RNE
    return __builtin_bit_cast(unsigned short, h);
}

// ---------------- fused prologue: transpose + edge histogram + weight pack --
__global__ __launch_bounds__(256) void k_transpose(const float* __restrict__ in,
                                                   unsigned short* __restrict__ x0,
                                                   const int* __restrict__ rows,
                                                   int* __restrict__ counts,
                                                   const float* __restrict__ weight,
                                                   unsigned short* __restrict__ wpack) {
    int tid = blockIdx.x * 256 + threadIdx.x;     // over V_*B_*8 groups of 4
    int f4 = tid & 7;
    int m  = tid >> 3;          // m = v*8 + b
    int v  = m >> 3;
    int b  = m & 7;
    float4 val = ((const float4*)(in + ((size_t)b * V_ + v) * FIN_))[f4];
    ushort4 o;
    o.x = f2bf(val.x); o.y = f2bf(val.y); o.z = f2bf(val.z); o.w = f2bf(val.w);
    ((ushort4*)x0)[tid] = o;

    if (tid < E_) atomicAdd(&counts[rows[tid]], 1);

    if (tid < 1024) {   // wpack[kq][ot][lane][j] = bf16(W[f=quad*8+j][kq][o=ot*16+l16])
        int lane = tid & 63;
        int ot   = (tid >> 6) & 3;
        int kq   = tid >> 8;
        int quad = lane >> 4, l16 = lane & 15;
        bf16x8 w;
        #pragma unroll
        for (int j = 0; j < 8; ++j)
            w[j] = (short)f2bf(weight[(size_t)(quad * 8 + j) * (K_ * FOUT_) + kq * FOUT_ + ot * 16 + l16]);
        *((bf16x8*)(wpack + (size_t)tid * 8)) = w;
    }
}

// ---------------- CSR build ------------------------------------------------
__global__ __launch_bounds__(256) void k_zero_int(int* __restrict__ p, int n) {
    int t = blockIdx.x * 256 + threadIdx.x;
    if (t < n) p[t] = 0;
}

// block-local exclusive scan; global offset = + boffs[idx>>10] applied
// downstream (k_scatter / k_spmm) -- no third scan pass needed.
__global__ __launch_bounds__(1024) void k_scan1(const int* __restrict__ counts,
                                                int* __restrict__ row_ptr,
                                                int* __restrict__ cursor,
                                                int* __restrict__ bsums, int n) {
    __shared__ int s[1024];
    int t = threadIdx.x;
    int idx = blockIdx.x * 1024 + t;
    int v = (idx < n) ? counts[idx] : 0;
    s[t] = v;
    __syncthreads();
    for (int off = 1; off < 1024; off <<= 1) {
        int add = (t >= off) ? s[t - off] : 0;
        __syncthreads();
        s[t] += add;
        __syncthreads();
    }
    if (idx < n) {
        int r = s[t] - v;   // exclusive, block-local
        row_ptr[idx] = r;
        cursor[idx]  = r;
    }
    if (t == 1023) bsums[blockIdx.x] = s[1023];
}

__global__ __launch_bounds__(128) void k_scan2(const int* __restrict__ bsums,
                                               int* __restrict__ boffs, int nb) {
    __shared__ int s[128];
    int t = threadIdx.x;
    int v = (t < nb) ? bsums[t] : 0;
    s[t] = v;
    __syncthreads();
    for (int off = 1; off < 128; off <<= 1) {
        int add = (t >= off) ? s[t - off] : 0;
        __syncthreads();
        s[t] += add;
        __syncthreads();
    }
    boffs[t] = s[t] - v;
}

__global__ __launch_bounds__(256) void k_scatter(const int* __restrict__ rows,
                                                 const int* __restrict__ cols,
                                                 const float* __restrict__ vals,
                                                 int* __restrict__ cursor,
                                                 const int* __restrict__ boffs,
                                                 int2* __restrict__ e_pack) {
    int e = blockIdx.x * 256 + threadIdx.x;
    if (e < E_) {
        int r = rows[e];
        int pos = atomicAdd(&cursor[r], 1) + boffs[r >> 10];
        e_pack[pos] = make_int2(cols[e], __float_as_int(vals[e]));
    }
}

// ---------------- SpMM body: full-wave per edge ----------------------------
// One edge per wave-iteration: 64 lanes x 8 B = 512 B single-segment gather.
// Lane l owns features [l*4, l*4+4).  4-deep unroll = 4 gathers in flight.
// acc updated in strict edge order (numerics-stable vs prior version).
static __device__ inline void spmm_row(const unsigned short* __restrict__ xc,
                                       const int2* __restrict__ ep,
                                       int beg, int end, int lane, float a[4]) {
    int e = beg;
    for (; e + 3 < end; e += 4) {
        int2 p0 = ep[e], p1 = ep[e + 1], p2 = ep[e + 2], p3 = ep[e + 3];
        ushort4 g0 = *((const ushort4*)(xc + (size_t)p0.x * NODE_F + lane * 4));
        ushort4 g1 = *((const ushort4*)(xc + (size_t)p1.x * NODE_F + lane * 4));
        ushort4 g2 = *((const ushort4*)(xc + (size_t)p2.x * NODE_F + lane * 4));
        ushort4 g3 = *((const ushort4*)(xc + (size_t)p3.x * NODE_F + lane * 4));
        float w0 = __int_as_float(p0.y), w1 = __int_as_float(p1.y);
        float w2 = __int_as_float(p2.y), w3 = __int_as_float(p3.y);
        a[0] += w0 * bf2f(g0.x); a[1] += w0 * bf2f(g0.y); a[2] += w0 * bf2f(g0.z); a[3] += w0 * bf2f(g0.w);
        a[0] += w1 * bf2f(g1.x); a[1] += w1 * bf2f(g1.y); a[2] += w1 * bf2f(g1.z); a[3] += w1 * bf2f(g1.w);
        a[0] += w2 * bf2f(g2.x); a[1] += w2 * bf2f(g2.y); a[2] += w2 * bf2f(g2.z); a[3] += w2 * bf2f(g2.w);
        a[0] += w3 * bf2f(g3.x); a[1] += w3 * bf2f(g3.y); a[2] += w3 * bf2f(g3.z); a[3] += w3 * bf2f(g3.w);
    }
    for (; e < end; ++e) {
        int2 p = ep[e];
        ushort4 g = *((const ushort4*)(xc + (size_t)p.x * NODE_F + lane * 4));
        float w = __int_as_float(p.y);
        a[0] += w * bf2f(g.x); a[1] += w * bf2f(g.y); a[2] += w * bf2f(g.z); a[3] += w * bf2f(g.w);
    }
}

// xn[v] = scale * (L @ xc)[v] - (has_prev ? xp[v] : 0)
__global__ __launch_bounds__(256) void k_spmm(const unsigned short* __restrict__ xc,
                                              const unsigned short* __restrict__ xp,
                                              const int* __restrict__ row_ptr,
                                              const int* __restrict__ boffs,
                                              const int2* __restrict__ ep,
                                              unsigned short* __restrict__ xn,
                                              float scale, int has_prev) {
    int wave = threadIdx.x >> 6;
    int lane = threadIdx.x & 63;
    int v = blockIdx.x * 4 + wave;
    if (v >= V_) return;
    int beg = row_ptr[v] + boffs[v >> 10];
    int end = (v == V_ - 1) ? E_ : row_ptr[v + 1] + boffs[(v + 1) >> 10];

    float a[4] = {0.f, 0.f, 0.f, 0.f};
    spmm_row(xc, ep, beg, end, lane, a);

    float r[4];
    if (has_prev) {
        ushort4 p = *((const ushort4*)(xp + (size_t)v * NODE_F + lane * 4));
        r[0] = scale * a[0] - bf2f(p.x);
        r[1] = scale * a[1] - bf2f(p.y);
        r[2] = scale * a[2] - bf2f(p.z);
        r[3] = scale * a[3] - bf2f(p.w);
    } else {
        r[0] = a[0]; r[1] = a[1]; r[2] = a[2]; r[3] = a[3];
    }
    ushort4 o;
    o.x = f2bf(r[0]); o.y = f2bf(r[1]); o.z = f2bf(r[2]); o.w = f2bf(r[3]);
    *((ushort4*)(xn + (size_t)v * NODE_F + lane * 4)) = o;
}

// ---------------- fused pass-3 SpMM + MFMA contraction ---------------------
// Each wave: compute x3 = 2*L*x2 - x1 for a node PAIR (v0, v0+1) -> LDS,
// then contract the 16 m-rows [pair*16, pair*16+16) with x0..x2 from global
// and x3 from LDS.  x3 never touches global memory.
// out[b,v,o] = sum_{kq,f} x_kq[m-row, f] * W[f,kq,o] + bias[o]
__global__ __launch_bounds__(256) void k_spmm3c(const unsigned short* __restrict__ x0,
                                                const unsigned short* __restrict__ x1,
                                                const unsigned short* __restrict__ x2,
                                                const int* __restrict__ row_ptr,
                                                const int* __restrict__ boffs,
                                                const int2* __restrict__ ep,
                                                const unsigned short* __restrict__ wpack,
                                                const float* __restrict__ bias,
                                                float* __restrict__ out) {
    __shared__ __align__(16) unsigned short x3s[4][2][NODE_F];   // 4 KB
    int wave = threadIdx.x >> 6;
    int lane = threadIdx.x & 63;
    int quad = lane >> 4;
    int l16  = lane & 15;
    int pair = blockIdx.x * 4 + wave;     // grid exact: 12500*4 = 50000 pairs
    int v0 = pair * 2;

    #pragma unroll 1
    for (int s = 0; s < 2; ++s) {
        int v = v0 + s;
        int beg = row_ptr[v] + boffs[v >> 10];
        int end = (v == V_ - 1) ? E_ : row_ptr[v + 1] + boffs[(v + 1) >> 10];
        float a[4] = {0.f, 0.f, 0.f, 0.f};
        spmm_row(x2, ep, beg, end, lane, a);
        ushort4 p1 = *((const ushort4*)(x1 + (size_t)v * NODE_F + lane * 4));
        ushort4 o;
        o.x = f2bf(2.f * a[0] - bf2f(p1.x));
        o.y = f2bf(2.f * a[1] - bf2f(p1.y));
        o.z = f2bf(2.f * a[2] - bf2f(p1.z));
        o.w = f2bf(2.f * a[3] - bf2f(p1.w));
        *((ushort4*)&x3s[wave][s][lane * 4]) = o;
    }
    __syncthreads();   // uniform: no early returns anywhere in this kernel

    // ---- contraction: m-rows [pair*16, pair*16+16) ----
    const unsigned short* xs012[3] = {x0, x1, x2};
    bf16x8 wfrag[4][4];
    #pragma unroll
    for (int kq = 0; kq < 4; ++kq)
        #pragma unroll
        for (int ot = 0; ot < 4; ++ot)
            wfrag[kq][ot] = *((const bf16x8*)(wpack + (size_t)((kq * 4 + ot) * 64 + lane) * 8));

    floatx4 acc[4];
    #pragma unroll
    for (int ot = 0; ot < 4; ++ot)
        acc[ot] = *((const floatx4*)(bias + ot * 16 + quad * 4));   // bias pre-seeded

    int m0 = pair * 16;
    #pragma unroll
    for (int kq = 0; kq < 4; ++kq) {
        bf16x8 xf;
        if (kq < 3)
            xf = *((const bf16x8*)(xs012[kq] + (size_t)(m0 + l16) * FIN_ + quad * 8));
        else
            xf = *((const bf16x8*)&x3s[wave][l16 >> 3][(l16 & 7) * FIN_ + quad * 8]);
        #pragma unroll
        for (int ot = 0; ot < 4; ++ot)
            acc[ot] = __builtin_amdgcn_mfma_f32_16x16x32_bf16(wfrag[kq][ot], xf, acc[ot], 0, 0, 0);
    }

    // D: col = lane&15 = m-row, row = quad*4+r = o  =>  float4 stores
    int m = m0 + l16;
    int v = m >> 3;
    int b = m & 7;
    float* op = out + ((size_t)b * V_ + v) * FOUT_ + quad * 4;
    #pragma unroll
    for (int ot = 0; ot < 4; ++ot)
        *((floatx4*)(op + ot * 16)) = acc[ot];
}

// ---------------- launcher -------------------------------------------------
extern "C" void kernel_launch(void* const* d_in, const int* in_sizes, int n_in,
                              void* d_out, int out_size, void* d_ws, size_t ws_size,
                              hipStream_t stream) {
    const float* inputs  = (const float*)d_in[0];
    const int*   laprows = (const int*)d_in[1];
    const int*   lapcols = (const int*)d_in[2];
    const float* lapvals = (const float*)d_in[3];
    const float* weight  = (const float*)d_in[4];
    const float* bias    = (const float*)d_in[5];
    float* out = (float*)d_out;

    const size_t XN = (size_t)V_ * NODE_F;   // 25.6M bf16 per buffer
    unsigned short* x0 = (unsigned short*)d_ws;
    unsigned short* x1 = x0 + XN;
    unsigned short* x2 = x1 + XN;
    int* counts  = (int*)(x2 + XN);
    int* row_ptr = counts + V_;
    int* cursor  = row_ptr + V_;
    int* bsums   = cursor + V_;
    int* boffs   = bsums + 128;
    int2* e_pack = (int2*)(boffs + 128);          // 8B-aligned
    unsigned short* wpack = (unsigned short*)(e_pack + E_);   // 16 KB

    const int NB_SCAN = (V_ + 1023) / 1024;   // 98

    hipLaunchKernelGGL(k_zero_int, dim3((V_ + 255) / 256), dim3(256), 0, stream, counts, V_);
    hipLaunchKernelGGL(k_transpose, dim3((V_ * B_ * 8) / 256), dim3(256), 0, stream,
                       inputs, x0, laprows, counts, weight, wpack);
    hipLaunchKernelGGL(k_scan1, dim3(NB_SCAN), dim3(1024), 0, stream,
                       counts, row_ptr, cursor, bsums, V_);
    hipLaunchKernelGGL(k_scan2, dim3(1), dim3(128), 0, stream, bsums, boffs, NB_SCAN);
    hipLaunchKernelGGL(k_scatter, dim3((E_ + 255) / 256), dim3(256), 0, stream,
                       laprows, lapcols, lapvals, cursor, boffs, e_pack);

    // x1 = L x0 ; x2 = 2 L x1 - x0 ; x3 fused into contraction
    hipLaunchKernelGGL(k_spmm, dim3(V_ / 4), dim3(256), 0, stream,
                       x0, (const unsigned short*)nullptr, row_ptr, boffs, e_pack, x1, 1.0f, 0);
    hipLaunchKernelGGL(k_spmm, dim3(V_ / 4), dim3(256), 0, stream,
                       x1, x0, row_ptr, boffs, e_pack, x2, 2.0f, 1);

    // 50000 node-pairs / 4 waves = 12500 blocks; pass-3 spmm + contraction
    hipLaunchKernelGGL(k_spmm3c, dim3(12500), dim3(256), 0, stream,
                       x0, x1, x2, row_ptr, boffs, e_pack, wpack, bias, out);
}

// Round 5
// 582.700 us; speedup vs baseline: 1.2948x; 1.0449x over previous
//
#include <hip/hip_runtime.h>
#include <hip/hip_bf16.h>

#define B_    8
#define V_    100000
#define FIN_  32
#define K_    4
#define FOUT_ 64
#define E_    800000
#define NODE_F 256   // B_ * FIN_ elements per node row

typedef __attribute__((ext_vector_type(8))) short bf16x8;
typedef __attribute__((ext_vector_type(4))) float floatx4;

static __device__ inline float bf2f(unsigned short u) {
    unsigned int x = ((unsigned int)u) << 16;
    return __builtin_bit_cast(float, x);
}
static __device__ inline unsigned short f2bf(float f) {
    __hip_bfloat16 h = __float2bfloat16(f);   // RNE
    return __builtin_bit_cast(unsigned short, h);
}

static __device__ inline float wave_max64(float m) {
    #pragma unroll
    for (int off = 1; off < 64; off <<= 1)
        m = fmaxf(m, __shfl_xor(m, off));
    return m;
}

// Quantize one node row (wave-wide, lane owns features [4*lane, 4*lane+4))
// to int8-biased-128 with per-row dequant scale d = max/127  (x ~= (u-128)*d).
static __device__ inline void quant_store(const float r[4], int v, int lane,
                                          unsigned char* __restrict__ xi,
                                          float* __restrict__ sc) {
    float m = fmaxf(fmaxf(fabsf(r[0]), fabsf(r[1])), fmaxf(fabsf(r[2]), fabsf(r[3])));
    m = wave_max64(m);
    float inv = (m > 0.f) ? 127.f / m : 0.f;
    if (lane == 0) sc[v] = (m > 0.f) ? m * (1.f / 127.f) : 0.f;
    unsigned int q = 0;
    #pragma unroll
    for (int j = 0; j < 4; ++j) {
        int qi = (int)rintf(r[j] * inv) + 128;   // in [1,255]
        q |= ((unsigned int)(qi & 0xff)) << (8 * j);
    }
    ((unsigned int*)(xi + (size_t)v * NODE_F))[lane] = q;
}

// ---------------- fused prologue: transpose + x0 quant + hist + weight pack -
__global__ __launch_bounds__(256) void k_transpose(const float* __restrict__ in,
                                                   unsigned short* __restrict__ x0,
                                                   unsigned char* __restrict__ x0i,
                                                   float* __restrict__ s0,
                                                   const int* __restrict__ rows,
                                                   int* __restrict__ counts,
                                                   const float* __restrict__ weight,
                                                   unsigned short* __restrict__ wpack) {
    int tid = blockIdx.x * 256 + threadIdx.x;     // over V_*B_*8 groups of 4
    int lane = threadIdx.x & 63;                  // wave == one node row
    int f4 = tid & 7;
    int m  = tid >> 3;          // m = v*8 + b
    int v  = m >> 3;
    int b  = m & 7;
    float4 val = ((const float4*)(in + ((size_t)b * V_ + v) * FIN_))[f4];
    ushort4 o;
    o.x = f2bf(val.x); o.y = f2bf(val.y); o.z = f2bf(val.z); o.w = f2bf(val.w);
    ((ushort4*)x0)[tid] = o;

    // int8 copy for the gather path (lane*4 == b*32 + f4*4, full row per wave)
    float r[4] = {val.x, val.y, val.z, val.w};
    quant_store(r, v, lane, x0i, s0);

    if (tid < E_) atomicAdd(&counts[rows[tid]], 1);

    if (tid < 1024) {   // wpack[kq][ot][lane][j] = bf16(W[f=quad*8+j][kq][o=ot*16+l16])
        int l = tid & 63;
        int ot   = (tid >> 6) & 3;
        int kq   = tid >> 8;
        int quad = l >> 4, l16 = l & 15;
        bf16x8 w;
        #pragma unroll
        for (int j = 0; j < 8; ++j)
            w[j] = (short)f2bf(weight[(size_t)(quad * 8 + j) * (K_ * FOUT_) + kq * FOUT_ + ot * 16 + l16]);
        *((bf16x8*)(wpack + (size_t)tid * 8)) = w;
    }
}

// ---------------- CSR build ------------------------------------------------
__global__ __launch_bounds__(256) void k_zero_int(int* __restrict__ p, int n) {
    int t = blockIdx.x * 256 + threadIdx.x;
    if (t < n) p[t] = 0;
}

// block-local exclusive scan; global offset = + boffs[idx>>10] applied
// downstream (k_scatter / k_spmm) -- no third scan pass needed.
__global__ __launch_bounds__(1024) void k_scan1(const int* __restrict__ counts,
                                                int* __restrict__ row_ptr,
                                                int* __restrict__ cursor,
                                                int* __restrict__ bsums, int n) {
    __shared__ int s[1024];
    int t = threadIdx.x;
    int idx = blockIdx.x * 1024 + t;
    int v = (idx < n) ? counts[idx] : 0;
    s[t] = v;
    __syncthreads();
    for (int off = 1; off < 1024; off <<= 1) {
        int add = (t >= off) ? s[t - off] : 0;
        __syncthreads();
        s[t] += add;
        __syncthreads();
    }
    if (idx < n) {
        int r = s[t] - v;   // exclusive, block-local
        row_ptr[idx] = r;
        cursor[idx]  = r;
    }
    if (t == 1023) bsums[blockIdx.x] = s[1023];
}

__global__ __launch_bounds__(128) void k_scan2(const int* __restrict__ bsums,
                                               int* __restrict__ boffs, int nb) {
    __shared__ int s[128];
    int t = threadIdx.x;
    int v = (t < nb) ? bsums[t] : 0;
    s[t] = v;
    __syncthreads();
    for (int off = 1; off < 128; off <<= 1) {
        int add = (t >= off) ? s[t - off] : 0;
        __syncthreads();
        s[t] += add;
        __syncthreads();
    }
    boffs[t] = s[t] - v;
}

__global__ __launch_bounds__(256) void k_scatter(const int* __restrict__ rows,
                                                 const int* __restrict__ cols,
                                                 const float* __restrict__ vals,
                                                 int* __restrict__ cursor,
                                                 const int* __restrict__ boffs,
                                                 int2* __restrict__ e_pack) {
    int e = blockIdx.x * 256 + threadIdx.x;
    if (e < E_) {
        int r = rows[e];
        int pos = atomicAdd(&cursor[r], 1) + boffs[r >> 10];
        e_pack[pos] = make_int2(cols[e], __float_as_int(vals[e]));
    }
}

// ---------------- SpMM body: int8 gathers, full-wave per edge --------------
// One edge per wave-iteration: 64 lanes x 4 B = 256 B row gather (2 lines).
// w_e = val_e * d[col];  S_j = sum_e w_e*(u_j - 128) = (sum w*u_j) - 128*sum(w).
static __device__ inline void spmm_row_i8(const unsigned char* __restrict__ xi,
                                          const float* __restrict__ sc,
                                          const int2* __restrict__ ep,
                                          int beg, int end, int lane,
                                          float a[4], float* swp) {
    float sw = 0.f;
    int e = beg;
    for (; e + 3 < end; e += 4) {
        int2 p0 = ep[e], p1 = ep[e + 1], p2 = ep[e + 2], p3 = ep[e + 3];
        unsigned int g0 = ((const unsigned int*)(xi + (size_t)p0.x * NODE_F))[lane];
        unsigned int g1 = ((const unsigned int*)(xi + (size_t)p1.x * NODE_F))[lane];
        unsigned int g2 = ((const unsigned int*)(xi + (size_t)p2.x * NODE_F))[lane];
        unsigned int g3 = ((const unsigned int*)(xi + (size_t)p3.x * NODE_F))[lane];
        float w0 = __int_as_float(p0.y) * sc[p0.x];
        float w1 = __int_as_float(p1.y) * sc[p1.x];
        float w2 = __int_as_float(p2.y) * sc[p2.x];
        float w3 = __int_as_float(p3.y) * sc[p3.x];
        sw += w0 + w1 + w2 + w3;
        a[0] += w0 * (float)(g0 & 0xff);         a[1] += w0 * (float)((g0 >> 8) & 0xff);
        a[2] += w0 * (float)((g0 >> 16) & 0xff); a[3] += w0 * (float)(g0 >> 24);
        a[0] += w1 * (float)(g1 & 0xff);         a[1] += w1 * (float)((g1 >> 8) & 0xff);
        a[2] += w1 * (float)((g1 >> 16) & 0xff); a[3] += w1 * (float)(g1 >> 24);
        a[0] += w2 * (float)(g2 & 0xff);         a[1] += w2 * (float)((g2 >> 8) & 0xff);
        a[2] += w2 * (float)((g2 >> 16) & 0xff); a[3] += w2 * (float)(g2 >> 24);
        a[0] += w3 * (float)(g3 & 0xff);         a[1] += w3 * (float)((g3 >> 8) & 0xff);
        a[2] += w3 * (float)((g3 >> 16) & 0xff); a[3] += w3 * (float)(g3 >> 24);
    }
    for (; e < end; ++e) {
        int2 p = ep[e];
        unsigned int g = ((const unsigned int*)(xi + (size_t)p.x * NODE_F))[lane];
        float w = __int_as_float(p.y) * sc[p.x];
        sw += w;
        a[0] += w * (float)(g & 0xff);         a[1] += w * (float)((g >> 8) & 0xff);
        a[2] += w * (float)((g >> 16) & 0xff); a[3] += w * (float)(g >> 24);
    }
    *swp = sw;
}

// xn = scale * (L @ xc) - (has_prev ? xp : 0);  writes bf16 + int8 copies.
__global__ __launch_bounds__(256) void k_spmm(const unsigned char* __restrict__ xci,
                                              const float* __restrict__ sci,
                                              const unsigned short* __restrict__ xp,
                                              const int* __restrict__ row_ptr,
                                              const int* __restrict__ boffs,
                                              const int2* __restrict__ ep,
                                              unsigned short* __restrict__ xn,
                                              unsigned char* __restrict__ xni,
                                              float* __restrict__ scn,
                                              float scale, int has_prev) {
    int wave = threadIdx.x >> 6;
    int lane = threadIdx.x & 63;
    int v = blockIdx.x * 4 + wave;          // grid exact: 25000*4 = V_
    int beg = row_ptr[v] + boffs[v >> 10];
    int end = (v == V_ - 1) ? E_ : row_ptr[v + 1] + boffs[(v + 1) >> 10];

    float a[4] = {0.f, 0.f, 0.f, 0.f};
    float sw;
    spmm_row_i8(xci, sci, ep, beg, end, lane, a, &sw);

    float r[4];
    #pragma unroll
    for (int j = 0; j < 4; ++j) r[j] = a[j] - 128.f * sw;   // true SpMM row
    if (has_prev) {
        ushort4 p = *((const ushort4*)(xp + (size_t)v * NODE_F + lane * 4));
        r[0] = scale * r[0] - bf2f(p.x);
        r[1] = scale * r[1] - bf2f(p.y);
        r[2] = scale * r[2] - bf2f(p.z);
        r[3] = scale * r[3] - bf2f(p.w);
    }
    ushort4 o;
    o.x = f2bf(r[0]); o.y = f2bf(r[1]); o.z = f2bf(r[2]); o.w = f2bf(r[3]);
    *((ushort4*)(xn + (size_t)v * NODE_F + lane * 4)) = o;
    quant_store(r, v, lane, xni, scn);
}

// ---------------- fused pass-3 SpMM + MFMA contraction ---------------------
// Each wave: x3 = 2*L*x2 - x1 for a node PAIR -> LDS (bf16), then contract
// the 16 m-rows with x0..x2 streamed from global and x3 from LDS.
// out stores are NON-TEMPORAL: 200 MB of writes must not evict the gather
// working set (x2 int8) from L2/L3.
__global__ __launch_bounds__(256) void k_spmm3c(const unsigned short* __restrict__ x0,
                                                const unsigned short* __restrict__ x1,
                                                const unsigned short* __restrict__ x2,
                                                const unsigned char* __restrict__ x2i,
                                                const float* __restrict__ s2,
                                                const int* __restrict__ row_ptr,
                                                const int* __restrict__ boffs,
                                                const int2* __restrict__ ep,
                                                const unsigned short* __restrict__ wpack,
                                                const float* __restrict__ bias,
                                                float* __restrict__ out) {
    __shared__ __align__(16) unsigned short x3s[4][2][NODE_F];   // 4 KB
    int wave = threadIdx.x >> 6;
    int lane = threadIdx.x & 63;
    int quad = lane >> 4;
    int l16  = lane & 15;
    int pair = blockIdx.x * 4 + wave;     // grid exact: 12500*4 = 50000 pairs
    int v0 = pair * 2;

    #pragma unroll 1
    for (int s = 0; s < 2; ++s) {
        int v = v0 + s;
        int beg = row_ptr[v] + boffs[v >> 10];
        int end = (v == V_ - 1) ? E_ : row_ptr[v + 1] + boffs[(v + 1) >> 10];
        float a[4] = {0.f, 0.f, 0.f, 0.f};
        float sw;
        spmm_row_i8(x2i, s2, ep, beg, end, lane, a, &sw);
        ushort4 p1 = *((const ushort4*)(x1 + (size_t)v * NODE_F + lane * 4));
        ushort4 o;
        o.x = f2bf(2.f * (a[0] - 128.f * sw) - bf2f(p1.x));
        o.y = f2bf(2.f * (a[1] - 128.f * sw) - bf2f(p1.y));
        o.z = f2bf(2.f * (a[2] - 128.f * sw) - bf2f(p1.z));
        o.w = f2bf(2.f * (a[3] - 128.f * sw) - bf2f(p1.w));
        *((ushort4*)&x3s[wave][s][lane * 4]) = o;
    }
    __syncthreads();   // uniform: no early returns in this kernel

    // ---- contraction: m-rows [pair*16, pair*16+16) ----
    const unsigned short* xs012[3] = {x0, x1, x2};
    bf16x8 wfrag[4][4];
    #pragma unroll
    for (int kq = 0; kq < 4; ++kq)
        #pragma unroll
        for (int ot = 0; ot < 4; ++ot)
            wfrag[kq][ot] = *((const bf16x8*)(wpack + (size_t)((kq * 4 + ot) * 64 + lane) * 8));

    floatx4 acc[4];
    #pragma unroll
    for (int ot = 0; ot < 4; ++ot)
        acc[ot] = *((const floatx4*)(bias + ot * 16 + quad * 4));   // bias pre-seeded

    int m0 = pair * 16;
    #pragma unroll
    for (int kq = 0; kq < 4; ++kq) {
        bf16x8 xf;
        if (kq < 3)
            xf = *((const bf16x8*)(xs012[kq] + (size_t)(m0 + l16) * FIN_ + quad * 8));
        else
            xf = *((const bf16x8*)&x3s[wave][l16 >> 3][(l16 & 7) * FIN_ + quad * 8]);
        #pragma unroll
        for (int ot = 0; ot < 4; ++ot)
            acc[ot] = __builtin_amdgcn_mfma_f32_16x16x32_bf16(wfrag[kq][ot], xf, acc[ot], 0, 0, 0);
    }

    // D: col = lane&15 = m-row, row = quad*4+r = o  =>  float4 nt-stores
    int m = m0 + l16;
    int v = m >> 3;
    int b = m & 7;
    float* op = out + ((size_t)b * V_ + v) * FOUT_ + quad * 4;
    #pragma unroll
    for (int ot = 0; ot < 4; ++ot)
        __builtin_nontemporal_store(acc[ot], (floatx4*)(op + ot * 16));
}

// ---------------- launcher -------------------------------------------------
extern "C" void kernel_launch(void* const* d_in, const int* in_sizes, int n_in,
                              void* d_out, int out_size, void* d_ws, size_t ws_size,
                              hipStream_t stream) {
    const float* inputs  = (const float*)d_in[0];
    const int*   laprows = (const int*)d_in[1];
    const int*   lapcols = (const int*)d_in[2];
    const float* lapvals = (const float*)d_in[3];
    const float* weight  = (const float*)d_in[4];
    const float* bias    = (const float*)d_in[5];
    float* out = (float*)d_out;

    const size_t XN  = (size_t)V_ * NODE_F;   // bf16 elements per buffer
    const size_t XNI = (size_t)V_ * NODE_F;   // int8 bytes per buffer
    unsigned short* x0 = (unsigned short*)d_ws;
    unsigned short* x1 = x0 + XN;
    unsigned short* x2 = x1 + XN;
    unsigned char* x0i = (unsigned char*)(x2 + XN);
    unsigned char* x1i = x0i + XNI;
    unsigned char* x2i = x1i + XNI;
    float* s0 = (float*)(x2i + XNI);
    float* s1 = s0 + V_;
    float* s2 = s1 + V_;
    int* counts  = (int*)(s2 + V_);
    int* row_ptr = counts + V_;
    int* cursor  = row_ptr + V_;
    int* bsums   = cursor + V_;
    int* boffs   = bsums + 128;
    unsigned short* wpack = (unsigned short*)(boffs + 128);   // 16 KB, 16B-aligned
    int2* e_pack = (int2*)(wpack + 8192);                     // 8B-aligned

    const int NB_SCAN = (V_ + 1023) / 1024;   // 98

    hipLaunchKernelGGL(k_zero_int, dim3((V_ + 255) / 256), dim3(256), 0, stream, counts, V_);
    hipLaunchKernelGGL(k_transpose, dim3((V_ * B_ * 8) / 256), dim3(256), 0, stream,
                       inputs, x0, x0i, s0, laprows, counts, weight, wpack);
    hipLaunchKernelGGL(k_scan1, dim3(NB_SCAN), dim3(1024), 0, stream,
                       counts, row_ptr, cursor, bsums, V_);
    hipLaunchKernelGGL(k_scan2, dim3(1), dim3(128), 0, stream, bsums, boffs, NB_SCAN);
    hipLaunchKernelGGL(k_scatter, dim3((E_ + 255) / 256), dim3(256), 0, stream,
                       laprows, lapcols, lapvals, cursor, boffs, e_pack);

    // x1 = L x0 ; x2 = 2 L x1 - x0 ; x3 fused into contraction
    hipLaunchKernelGGL(k_spmm, dim3(V_ / 4), dim3(256), 0, stream,
                       x0i, s0, (const unsigned short*)nullptr, row_ptr, boffs, e_pack,
                       x1, x1i, s1, 1.0f, 0);
    hipLaunchKernelGGL(k_spmm, dim3(V_ / 4), dim3(256), 0, stream,
                       x1i, s1, x0, row_ptr, boffs, e_pack,
                       x2, x2i, s2, 2.0f, 1);

    // 50000 node-pairs / 4 waves = 12500 blocks; pass-3 spmm + contraction
    hipLaunchKernelGGL(k_spmm3c, dim3(12500), dim3(256), 0, stream,
                       x0, x1, x2, x2i, s2, row_ptr, boffs, e_pack, wpack, bias, out);
}